// Round 8
// baseline (3274.620 us; speedup 1.0000x reference)
//
#include <hip/hip_runtime.h>
#include <math.h>
#include <stdint.h>

// ============================================================================
// TopDownNet via split-f16 MFMA, R12: 32-sample blocks + affordable prefetch.
// History: R9 (2407us, best): of-eighth, 16x16x32, acc64 -> total regs exactly
// 128 (the hard 16-waves/CU ceiling; R8 vs R9 calibrated: <=128 -> 16 w/CU,
// >128 -> 8 w/CU). No slack -> no prefetch -> chunk-boundary L2 latency
// exposed (MfmaUtil 57%). R10 (2x weight loads, no prefetch): regressed.
// R11 (32x32 + prefetch at the 128 cap): compiler spilled (+3.4GB scratch
// traffic), regressed; absmax also 3x worse. R12:
//  - block = 32 samples x 8 waves (4096 blocks); wave = 2 nt-tiles x 2 sf
//    -> acc 32 regs; LDS 38.4KB -> 2 blocks/CU resident at only 77KB.
//  - freed ~32 regs fund a 2-deep weight prefetch (named A/B bufs) that FITS
//    under 128 -> L2-hit latency hidden, no spill.
//  - weight traffic 2x (L2-resident, ~27 TB/s < 34.5 ceiling) - latency paid
//    once, bandwidth ok. LDS demand per sample unchanged. MFMA total same.
// Split math (validated R5-R10, absmax 3.8e-6): x = xh + xl*2^-11, w likewise;
//   acc1 += xh*wh ; acc2 += xh*wl + xl*wh ; result = acc1 + acc2/2048.
// Fragment layouts (gfx950 16x16x32): A row=l&15 (of), k=(l>>4)*8+i;
//   B col=l&15 (sample), same k; D row=(l>>4)*4+r, col=l&15.
// ============================================================================

typedef _Float16 half8 __attribute__((ext_vector_type(8)));
typedef __fp16 fp16x2 __attribute__((ext_vector_type(2)));  // cvt_pkrtz native
typedef float f32x4 __attribute__((ext_vector_type(4)));

constexpr int KS = 10;
constexpr int RSTR = 584;  // f16/row: 288 hi + 288 lo + 8 pad
constexpr float SPLIT_S = 2048.f;
constexpr float SPLIT_INV = 1.f / 2048.f;

// W^T fragment streams (16x16 layout, verified R5-R10).
// Frag idx within layer: f = c*16 + nt. Layer bases: O1 0, M1 144, O2 288,
// M2 416, M3 544. Frag = 64 lanes x 8 f16 (1KB).
__device__ __align__(16) _Float16 g_Wh[672 * 512];
__device__ __align__(16) _Float16 g_Wl[672 * 512];
// M1 park: 4096 blocks x 8 waves x 4 uint4 x 64 lanes = 134 MB (wave-private).
__device__ __align__(16) uint4 g_park[4096u * 8u * 4u * 64u];

__global__ void prep_w(const float* __restrict__ O1w, const float* __restrict__ M1w,
                       const float* __restrict__ O2w, const float* __restrict__ M2w,
                       const float* __restrict__ M3w) {
  const int bid = blockIdx.x, l = threadIdx.x;
  const float* W; int Ksrc, f;
  if (bid < 144)      { W = O1w; Ksrc = 270; f = bid; }
  else if (bid < 288) { W = M1w; Ksrc = 270; f = bid - 144; }
  else if (bid < 416) { W = O2w; Ksrc = 256; f = bid - 288; }
  else if (bid < 544) { W = M2w; Ksrc = 256; f = bid - 416; }
  else                { W = M3w; Ksrc = 256; f = bid - 544; }
  const int c = f >> 4, nt = f & 15, g = l >> 4, s = l & 15;
  const int of = nt * 16 + s;
  union { half8 h; uint4 u; } hv, lv;
#pragma unroll
  for (int i = 0; i < 8; ++i) {
    const int k = c * 32 + g * 8 + i;
    const float w = (k < Ksrc) ? W[k * 256 + of] : 0.f;  // zero-pad K 270..287
    const _Float16 h = (_Float16)w;
    hv.h[i] = h;
    lv.h[i] = (_Float16)((w - (float)h) * SPLIT_S);
  }
  ((uint4*)g_Wh)[bid * 64 + l] = hv.u;
  ((uint4*)g_Wl)[bid * 64 + l] = lv.u;
}

__device__ __forceinline__ half8 as_half8(uint4 u) {
  union { uint4 u4; half8 h; } c; c.u4 = u; return c.h;
}
__device__ __forceinline__ f32x4 mfma16(half8 a, half8 b, f32x4 c) {
  return __builtin_amdgcn_mfma_f32_16x16x32_f16(a, b, c, 0, 0, 0);
}
__device__ __forceinline__ uint32_t h2bits(fp16x2 h) {
  union { fp16x2 h2; uint32_t u; } c; c.h2 = h; return c.u;
}

struct PK { uint2 hi, lo; };
// RTZ split-pack of 4 f32 -> 4 f16-hi + 4 f16-lo (residual * 2048).
__device__ __forceinline__ PK split4(float v0, float v1, float v2, float v3) {
  fp16x2 h01 = __builtin_amdgcn_cvt_pkrtz(v0, v1);
  fp16x2 h23 = __builtin_amdgcn_cvt_pkrtz(v2, v3);
  fp16x2 l01 = __builtin_amdgcn_cvt_pkrtz((v0 - (float)h01[0]) * SPLIT_S,
                                          (v1 - (float)h01[1]) * SPLIT_S);
  fp16x2 l23 = __builtin_amdgcn_cvt_pkrtz((v2 - (float)h23[0]) * SPLIT_S,
                                          (v3 - (float)h23[1]) * SPLIT_S);
  PK r;
  r.hi = make_uint2(h2bits(h01), h2bits(h23));
  r.lo = make_uint2(h2bits(l01), h2bits(l23));
  return r;
}
__device__ __forceinline__ void split1(float v, _Float16& h, _Float16& l) {
  h = (_Float16)v;
  l = (_Float16)((v - (float)h) * SPLIT_S);
}

// Per-chunk weight set: 2 nt-tiles x hi/lo planes (4 dwordx4).
struct W2 { uint4 h0, h1, l0, l1; };
__device__ __forceinline__ W2 ldw2(const uint4* __restrict__ Wh,
                                   const uint4* __restrict__ Wl, int fb) {
  W2 w;
  w.h0 = Wh[fb * 64];
  w.h1 = Wh[(fb + 1) * 64];
  w.l0 = Wl[fb * 64];
  w.l1 = Wl[(fb + 1) * 64];
  return w;
}

// One K-chunk: 4 ds_read_b128 + 12 MFMA.
__device__ __forceinline__ void body(f32x4 a1[2][2], f32x4 a2[2][2],
                                     const W2& w,
                                     const _Float16* __restrict__ Xp0,
                                     const _Float16* __restrict__ Xp1,
                                     int coff) {
  const half8 wh0 = as_half8(w.h0), wh1 = as_half8(w.h1);
  const half8 wl0 = as_half8(w.l0), wl1 = as_half8(w.l1);
  {
    half8 bh = *(const half8*)(Xp0 + coff);
    half8 bl = *(const half8*)(Xp0 + coff + 288);
    a1[0][0] = mfma16(wh0, bh, a1[0][0]);
    a2[0][0] = mfma16(wh0, bl, a2[0][0]);
    a2[0][0] = mfma16(wl0, bh, a2[0][0]);
    a1[1][0] = mfma16(wh1, bh, a1[1][0]);
    a2[1][0] = mfma16(wh1, bl, a2[1][0]);
    a2[1][0] = mfma16(wl1, bh, a2[1][0]);
  }
  {
    half8 bh = *(const half8*)(Xp1 + coff);
    half8 bl = *(const half8*)(Xp1 + coff + 288);
    a1[0][1] = mfma16(wh0, bh, a1[0][1]);
    a2[0][1] = mfma16(wh0, bl, a2[0][1]);
    a2[0][1] = mfma16(wl0, bh, a2[0][1]);
    a1[1][1] = mfma16(wh1, bh, a1[1][1]);
    a2[1][1] = mfma16(wh1, bl, a2[1][1]);
    a2[1][1] = mfma16(wl1, bh, a2[1][1]);
  }
}

// GEMM over CHUNKS K-chunks of 32 with 2-deep weight prefetch (named bufs).
template <int CHUNKS>
__device__ __forceinline__ void lgemm(f32x4 a1[2][2], f32x4 a2[2][2],
                                      const _Float16* __restrict__ Xp0,
                                      const _Float16* __restrict__ Xp1,
                                      const uint4* __restrict__ Wh,
                                      const uint4* __restrict__ Wl, int wu) {
  W2 A = ldw2(Wh, Wl, 2 * wu);  // chunk 0
  W2 B;
#pragma unroll 1
  for (int c = 0; c + 2 <= CHUNKS; c += 2) {
    B = ldw2(Wh, Wl, 16 * (c + 1) + 2 * wu);
    body(a1, a2, A, Xp0, Xp1, c * 32);
    if (c + 2 < CHUNKS) A = ldw2(Wh, Wl, 16 * (c + 2) + 2 * wu);
    body(a1, a2, B, Xp0, Xp1, (c + 1) * 32);
  }
  if (CHUNKS & 1) body(a1, a2, A, Xp0, Xp1, (CHUNKS - 1) * 32);
}

__device__ __forceinline__ void zero22(f32x4 a1[2][2], f32x4 a2[2][2]) {
#pragma unroll
  for (int n = 0; n < 2; ++n)
#pragma unroll
    for (int sf = 0; sf < 2; ++sf) {
      a1[n][sf] = (f32x4){0.f, 0.f, 0.f, 0.f};
      a2[n][sf] = (f32x4){0.f, 0.f, 0.f, 0.f};
    }
}

// relu(acc1 + acc2/2048 + bias) split-packed into X planes.
__device__ __forceinline__ void epi_write(const f32x4 a1[2][2], const f32x4 a2[2][2],
                                          const float* __restrict__ bias,  // global
                                          _Float16* __restrict__ Xs,
                                          int wu, int g, int s) {
#pragma unroll
  for (int n = 0; n < 2; ++n) {
    const float4 bv = *(const float4*)(bias + (2 * wu + n) * 16 + 4 * g);
#pragma unroll
    for (int sf = 0; sf < 2; ++sf) {
      const float v0 = fmaxf(fmaf(a2[n][sf][0], SPLIT_INV, a1[n][sf][0]) + bv.x, 0.f);
      const float v1 = fmaxf(fmaf(a2[n][sf][1], SPLIT_INV, a1[n][sf][1]) + bv.y, 0.f);
      const float v2 = fmaxf(fmaf(a2[n][sf][2], SPLIT_INV, a1[n][sf][2]) + bv.z, 0.f);
      const float v3 = fmaxf(fmaf(a2[n][sf][3], SPLIT_INV, a1[n][sf][3]) + bv.w, 0.f);
      const PK p = split4(v0, v1, v2, v3);
      _Float16* yp = Xs + (16 * sf + s) * RSTR + (2 * wu + n) * 16 + 4 * g;
      *(uint2*)yp = p.hi;
      *(uint2*)(yp + 288) = p.lo;
    }
  }
}

// M1 epilogue -> coalesced park in global (wave-private slot, 4 uint4/lane).
__device__ __forceinline__ void epi_park(const f32x4 a1[2][2], const f32x4 a2[2][2],
                                         const float* __restrict__ bias,
                                         uint4* __restrict__ slot,
                                         int wu, int g, int l) {
#pragma unroll
  for (int n = 0; n < 2; ++n) {
    const float4 bv = *(const float4*)(bias + (2 * wu + n) * 16 + 4 * g);
    PK q[2];
#pragma unroll
    for (int sf = 0; sf < 2; ++sf) {
      const float v0 = fmaxf(fmaf(a2[n][sf][0], SPLIT_INV, a1[n][sf][0]) + bv.x, 0.f);
      const float v1 = fmaxf(fmaf(a2[n][sf][1], SPLIT_INV, a1[n][sf][1]) + bv.y, 0.f);
      const float v2 = fmaxf(fmaf(a2[n][sf][2], SPLIT_INV, a1[n][sf][2]) + bv.z, 0.f);
      const float v3 = fmaxf(fmaf(a2[n][sf][3], SPLIT_INV, a1[n][sf][3]) + bv.w, 0.f);
      q[sf] = split4(v0, v1, v2, v3);
    }
    slot[n * 64 + l]       = make_uint4(q[0].hi.x, q[0].hi.y, q[1].hi.x, q[1].hi.y);
    slot[(2 + n) * 64 + l] = make_uint4(q[0].lo.x, q[0].lo.y, q[1].lo.x, q[1].lo.y);
  }
}

// unpark loaded uint4s -> X planes.
__device__ __forceinline__ void unpark_write(const uint4 pk[4],
                                             _Float16* __restrict__ Xs,
                                             int wu, int g, int s) {
#pragma unroll
  for (int n = 0; n < 2; ++n) {
    const uint4 hi = pk[n];
    const uint4 lo = pk[2 + n];
#pragma unroll
    for (int sf = 0; sf < 2; ++sf) {
      _Float16* yp = Xs + (16 * sf + s) * RSTR + (2 * wu + n) * 16 + 4 * g;
      *(uint2*)yp = sf ? make_uint2(hi.z, hi.w) : make_uint2(hi.x, hi.y);
      *(uint2*)(yp + 288) = sf ? make_uint2(lo.z, lo.w) : make_uint2(lo.x, lo.y);
    }
  }
}

__global__ __launch_bounds__(512, 4) void topdown_mfma(
    const float* __restrict__ towers, const float* __restrict__ aggregate,
    const float* __restrict__ O1b, const float* __restrict__ O2b,
    const float* __restrict__ O3w, const float* __restrict__ O3b,
    const float* __restrict__ M1b, const float* __restrict__ M2b,
    const float* __restrict__ M3b, float* __restrict__ out) {
  __shared__ __align__(16) _Float16 Xs[32 * RSTR];  // 37376 B
  __shared__ __align__(16) float scr[32][8];        // 1 KB cross-wave reduce
  const int t = threadIdx.x, l = t & 63;
  const int wu = __builtin_amdgcn_readfirstlane(t >> 6);  // wave id = of-eighth
  const int g = l >> 4, s = l & 15;
  const int n0 = blockIdx.x * 32;
  uint4* park = g_park + ((size_t)blockIdx.x * 8 + (size_t)wu) * (4 * 64);

  // per-lane B-read bases: rows s (sf=0) and 16+s (sf=1), k-offset g*8
  const _Float16* Xp0 = Xs + s * RSTR + g * 8;
  const _Float16* Xp1 = Xs + (16 + s) * RSTR + g * 8;

  // init X: logical features 0..255 = aggregate, 256..287 = 0 (both planes).
  for (int idx = t; idx < 32 * 288; idx += 512) {
    const int ss = idx / 288, f = idx - ss * 288;
    const float v = (f < 256) ? aggregate[f] : 0.f;
    _Float16 h, lo; split1(v, h, lo);
    Xs[ss * RSTR + f] = h;
    Xs[ss * RSTR + 288 + f] = lo;
  }

  float prod = 1.f;
  const float o3bias = O3b[0];
  f32x4 a1[2][2], a2[2][2];

  const uint4* WhL = (const uint4*)g_Wh + l;
  const uint4* WlL = (const uint4*)g_Wl + l;

  for (int kk = 0; kk < KS; ++kk) {
    const int tbase = (KS - 1 - kk) * 14;  // reference flips along K
    // tower slice -> logical features 256..269 (both planes); 448 elems
    if (t < 448) {
      const int ss = t / 14, f = t - ss * 14;
      const float v = towers[(size_t)(n0 + ss) * (KS * 14) + tbase + f];
      _Float16 h, lo; split1(v, h, lo);
      Xs[ss * RSTR + 256 + f] = h;
      Xs[ss * RSTR + 288 + 256 + f] = lo;
    }
    __syncthreads();  // (a) towers + previous A' visible

    // ---- M1 over X=[A,T]; result -> global park
    zero22(a1, a2);
    lgemm<9>(a1, a2, Xp0, Xp1, WhL + 144 * 64, WlL + 144 * 64, wu);
    epi_park(a1, a2, M1b, park, wu, g, l);

    // ---- O1 over X
    zero22(a1, a2);
    lgemm<9>(a1, a2, Xp0, Xp1, WhL, WlL, wu);
    __syncthreads();  // (b) all X reads done; park stores drained (vmcnt0)
    epi_write(a1, a2, O1b, Xs, wu, g, s);  // X[0..255] <- h1
    __syncthreads();  // (c) h1 visible

    // ---- O2 over h1
    zero22(a1, a2);
    lgemm<8>(a1, a2, Xp0, Xp1, WhL + 288 * 64, WlL + 288 * 64, wu);

    // unpark loads issued now (wave-private; latency hides under O3 tail)
    asm volatile("" ::: "memory");
    uint4 pk[4];
#pragma unroll
    for (int q = 0; q < 4; ++q) pk[q] = park[q * 64 + l];

    // O3 tail: relu(O2) dot O3w over this wave's 32 of -> per-sample partials
    float tp[2] = {0.f, 0.f};
#pragma unroll
    for (int n = 0; n < 2; ++n) {
      const int ob = (2 * wu + n) * 16 + 4 * g;
      const float4 bv = *(const float4*)(O2b + ob);
      const float4 ov = *(const float4*)(O3w + ob);
      const float bb[4] = {bv.x, bv.y, bv.z, bv.w};
      const float oo[4] = {ov.x, ov.y, ov.z, ov.w};
#pragma unroll
      for (int sf = 0; sf < 2; ++sf)
#pragma unroll
        for (int r = 0; r < 4; ++r)
          tp[sf] += fmaxf(fmaf(a2[n][sf][r], SPLIT_INV, a1[n][sf][r]) + bb[r], 0.f) * oo[r];
    }
#pragma unroll
    for (int sf = 0; sf < 2; ++sf) {  // sum over the 4 g-groups
      tp[sf] += __shfl_xor(tp[sf], 16);
      tp[sf] += __shfl_xor(tp[sf], 32);
    }
    if (g == 0) {
      scr[s][wu] = tp[0];
      scr[16 + s][wu] = tp[1];
    }
    __syncthreads();  // (d) scr ready; all h1 reads done

    unpark_write(pk, Xs, wu, g, s);  // X <- A' (M1 result)
    if (t < 32) {
      const float4 s0 = *(const float4*)(scr[t]);
      const float4 s1 = *(const float4*)(scr[t] + 4);
      const float tt = ((s0.x + s0.y) + (s0.z + s0.w)) +
                       ((s1.x + s1.y) + (s1.z + s1.w)) + o3bias;
      prod *= 1.f / (1.f + expf(-tt));
    }
    __syncthreads();  // (e) A' visible

    // ---- M2 (in place)
    zero22(a1, a2);
    lgemm<8>(a1, a2, Xp0, Xp1, WhL + 416 * 64, WlL + 416 * 64, wu);
    __syncthreads();  // (f) reads done
    epi_write(a1, a2, M2b, Xs, wu, g, s);
    __syncthreads();  // (g)

    // ---- M3 (in place); next-iter sync (a) covers the write->read edge
    zero22(a1, a2);
    lgemm<8>(a1, a2, Xp0, Xp1, WhL + 544 * 64, WlL + 544 * 64, wu);
    __syncthreads();  // (h) reads done
    epi_write(a1, a2, M3b, Xs, wu, g, s);
  }

  if (t < 32) out[n0 + t] = prod;
}

extern "C" void kernel_launch(void* const* d_in, const int* in_sizes, int n_in,
                              void* d_out, int out_size, void* d_ws, size_t ws_size,
                              hipStream_t stream) {
  const float* towers    = (const float*)d_in[0];
  const float* aggregate = (const float*)d_in[1];
  const float* M1w = (const float*)d_in[2];
  const float* M1b = (const float*)d_in[3];
  const float* M2w = (const float*)d_in[4];
  const float* M2b = (const float*)d_in[5];
  const float* M3w = (const float*)d_in[6];
  const float* M3b = (const float*)d_in[7];
  const float* O1w = (const float*)d_in[8];
  const float* O1b = (const float*)d_in[9];
  const float* O2w = (const float*)d_in[10];
  const float* O2b = (const float*)d_in[11];
  const float* O3w = (const float*)d_in[12];
  const float* O3b = (const float*)d_in[13];
  float* out = (float*)d_out;

  prep_w<<<672, 64, 0, stream>>>(O1w, M1w, O2w, M2w, M3w);

  const int nblocks = out_size / 32;  // 4096 blocks x 512 threads (8 waves)
  topdown_mfma<<<nblocks, 512, 0, stream>>>(towers, aggregate, O1b, O2b, O3w,
                                            O3b, M1b, M2b, M3b, out);
}

// Round 9
// 3052.443 us; speedup vs baseline: 1.0728x; 1.0728x over previous
//
#include <hip/hip_runtime.h>
#include <math.h>
#include <stdint.h>

// ============================================================================
// TopDownNet via split-f16 MFMA, R13: 32x32x16 MFMA, R9 decomposition, NO
// manual prefetch.
// Evidence chain: R9 (2407us best): 16x16x32, of-eighth, 64-sample block,
// MfmaUtil 57 + VALUBusy 38 = issue-saturated. R10/R12: raising per-wave
// weight-load:MFMA ratio always loses. R11 (32x32 + manual W4 prefetch):
// +32 regs broke the 128-reg/wave occupancy cap -> compiler spilled the
// prefetch buffers (FETCH/WRITE +3.4GB) -> regressed; BUT it validated the
// 32x32 fragment layout + numerics (passed, absmax 1.14e-5 < 2.2e-5).
// R13 = R11 minus prefetch: per-chunk direct weight loads (R9 style).
//  - MFMA insts per chunk 24 -> 12 (pipe demand 1.30 -> 1.08 ms; issue slots
//    halve -> VALU gets issue room).
//  - weight bytes + LDS reads per chunk UNCHANGED vs R9.
//  - live regs ~110 < 128 -> 16 waves/CU, no spill (check: WRITE ~1.5GB).
// D layout 32x32 (m74/m101): col=l&31, row=(r&3)+8*(r>>2)+4*(l>>5).
// A: row(of)=l&31, k=(l>>5)*8+i ; B: col(sample)=l&31, same k.
// Split math: x = xh + xl*2^-11, w likewise;
//   acc1 += xh*wh ; acc2 += xh*wl + xl*wh ; result = acc1 + acc2/2048.
// ============================================================================

typedef _Float16 half8 __attribute__((ext_vector_type(8)));
typedef __fp16 fp16x2 __attribute__((ext_vector_type(2)));  // cvt_pkrtz native
typedef float f32x16 __attribute__((ext_vector_type(16)));

constexpr int KS = 10;
constexpr int RSTR = 584;  // f16/row: 288 hi + 288 lo + 8 pad
constexpr float SPLIT_S = 2048.f;
constexpr float SPLIT_INV = 1.f / 2048.f;

// W^T fragment streams for 32x32: frag = 32 of x 16 k, 64 lanes x 8 f16 (1KB).
// Within layer: frag f = kc*8 + ot (kc = k/16, ot = of/32).
// Layer bases (frags): O1 0, M1 144, O2 288, M2 416, M3 544 (total 672).
__device__ __align__(16) _Float16 g_Wh[672 * 512];
__device__ __align__(16) _Float16 g_Wl[672 * 512];
// M1 park: 2048 blocks x 8 waves x 8 uint4 x 64 lanes (wave-private slots).
__device__ __align__(16) uint4 g_park[2048u * 8u * 8u * 64u];

__global__ void prep_w(const float* __restrict__ O1w, const float* __restrict__ M1w,
                       const float* __restrict__ O2w, const float* __restrict__ M2w,
                       const float* __restrict__ M3w) {
  const int bid = blockIdx.x, l = threadIdx.x;
  const float* W; int Ksrc, f;
  if (bid < 144)      { W = O1w; Ksrc = 270; f = bid; }
  else if (bid < 288) { W = M1w; Ksrc = 270; f = bid - 144; }
  else if (bid < 416) { W = O2w; Ksrc = 256; f = bid - 288; }
  else if (bid < 544) { W = M2w; Ksrc = 256; f = bid - 416; }
  else                { W = M3w; Ksrc = 256; f = bid - 544; }
  const int kc = f >> 3, ot = f & 7;
  const int of = ot * 32 + (l & 31);      // A row = l&31
  const int kb = kc * 16 + (l >> 5) * 8;  // A k = (l>>5)*8 + i
  union { half8 h; uint4 u; } hv, lv;
#pragma unroll
  for (int i = 0; i < 8; ++i) {
    const int k = kb + i;
    const float w = (k < Ksrc) ? W[k * 256 + of] : 0.f;  // zero-pad K tail
    const _Float16 h = (_Float16)w;
    hv.h[i] = h;
    lv.h[i] = (_Float16)((w - (float)h) * SPLIT_S);
  }
  ((uint4*)g_Wh)[bid * 64 + l] = hv.u;
  ((uint4*)g_Wl)[bid * 64 + l] = lv.u;
}

__device__ __forceinline__ half8 as_half8(uint4 u) {
  union { uint4 u4; half8 h; } c; c.u4 = u; return c.h;
}
__device__ __forceinline__ f32x16 mfma32(half8 a, half8 b, f32x16 c) {
  return __builtin_amdgcn_mfma_f32_32x32x16_f16(a, b, c, 0, 0, 0);
}
__device__ __forceinline__ uint32_t h2bits(fp16x2 h) {
  union { fp16x2 h2; uint32_t u; } c; c.h2 = h; return c.u;
}

struct PK { uint2 hi, lo; };
// RTZ split-pack of 4 f32 -> 4 f16-hi + 4 f16-lo (residual * 2048).
__device__ __forceinline__ PK split4(float v0, float v1, float v2, float v3) {
  fp16x2 h01 = __builtin_amdgcn_cvt_pkrtz(v0, v1);
  fp16x2 h23 = __builtin_amdgcn_cvt_pkrtz(v2, v3);
  fp16x2 l01 = __builtin_amdgcn_cvt_pkrtz((v0 - (float)h01[0]) * SPLIT_S,
                                          (v1 - (float)h01[1]) * SPLIT_S);
  fp16x2 l23 = __builtin_amdgcn_cvt_pkrtz((v2 - (float)h23[0]) * SPLIT_S,
                                          (v3 - (float)h23[1]) * SPLIT_S);
  PK r;
  r.hi = make_uint2(h2bits(h01), h2bits(h23));
  r.lo = make_uint2(h2bits(l01), h2bits(l23));
  return r;
}
__device__ __forceinline__ void split1(float v, _Float16& h, _Float16& l) {
  h = (_Float16)v;
  l = (_Float16)((v - (float)h) * SPLIT_S);
}

// One K-chunk of 32: 4 global dwordx4 (weights) + 8 ds_read_b128 + 12 MFMA.
__device__ __forceinline__ void body32(f32x16& a10, f32x16& a11,
                                       f32x16& a20, f32x16& a21,
                                       const _Float16* __restrict__ Xp0,
                                       const _Float16* __restrict__ Xp1,
                                       int coff,
                                       const uint4* __restrict__ Wh,
                                       const uint4* __restrict__ Wl, int fb) {
#pragma unroll
  for (int kk = 0; kk < 2; ++kk) {
    const half8 wh = as_half8(Wh[(fb + kk * 8) * 64]);
    const half8 wl = as_half8(Wl[(fb + kk * 8) * 64]);
    const int o = coff + kk * 16;
    half8 bh0 = *(const half8*)(Xp0 + o);
    half8 bl0 = *(const half8*)(Xp0 + o + 288);
    a10 = mfma32(wh, bh0, a10);
    a20 = mfma32(wh, bl0, a20);
    a20 = mfma32(wl, bh0, a20);
    half8 bh1 = *(const half8*)(Xp1 + o);
    half8 bl1 = *(const half8*)(Xp1 + o + 288);
    a11 = mfma32(wh, bh1, a11);
    a21 = mfma32(wh, bl1, a21);
    a21 = mfma32(wl, bh1, a21);
  }
}

// GEMM over CHUNKS K-chunks (no manual prefetch; compiler schedules loads).
template <int CHUNKS>
__device__ __forceinline__ void lgemm32(f32x16& a10, f32x16& a11,
                                        f32x16& a20, f32x16& a21,
                                        const _Float16* __restrict__ Xp0,
                                        const _Float16* __restrict__ Xp1,
                                        const uint4* __restrict__ Wh,
                                        const uint4* __restrict__ Wl, int wu) {
#pragma unroll 1
  for (int c = 0; c < CHUNKS; ++c)
    body32(a10, a11, a20, a21, Xp0, Xp1, c * 32, Wh, Wl, 16 * c + wu);
}

__device__ __forceinline__ void zero2(f32x16& a, f32x16& b) {
#pragma unroll
  for (int i = 0; i < 16; ++i) { a[i] = 0.f; b[i] = 0.f; }
}

// relu(a1 + a2/2048 + bias) split-packed into X planes.
// Lane holds: sample col = l&31 (per sf), of = 32wu + 8q + 4hi + j (r=4q+j).
__device__ __forceinline__ void epi_write(const f32x16 a1[2], const f32x16 a2[2],
                                          const float* __restrict__ bias,
                                          _Float16* __restrict__ Xs,
                                          int wu, int col, int hi) {
#pragma unroll
  for (int sf = 0; sf < 2; ++sf) {
    _Float16* yrow = Xs + (32 * sf + col) * RSTR;
#pragma unroll
    for (int q = 0; q < 4; ++q) {
      const int ofb = 32 * wu + 8 * q + 4 * hi;
      const float4 bv = *(const float4*)(bias + ofb);
      const float v0 = fmaxf(fmaf(a2[sf][4*q+0], SPLIT_INV, a1[sf][4*q+0]) + bv.x, 0.f);
      const float v1 = fmaxf(fmaf(a2[sf][4*q+1], SPLIT_INV, a1[sf][4*q+1]) + bv.y, 0.f);
      const float v2 = fmaxf(fmaf(a2[sf][4*q+2], SPLIT_INV, a1[sf][4*q+2]) + bv.z, 0.f);
      const float v3 = fmaxf(fmaf(a2[sf][4*q+3], SPLIT_INV, a1[sf][4*q+3]) + bv.w, 0.f);
      const PK p = split4(v0, v1, v2, v3);
      *(uint2*)(yrow + ofb) = p.hi;
      *(uint2*)(yrow + 288 + ofb) = p.lo;
    }
  }
}

// M1 epilogue -> coalesced park in global (wave-private slot, 8 uint4/lane).
// slot[sf*2+qq] = hi of q=2qq (.xy) and q=2qq+1 (.zw); slot[4+..] = lo.
__device__ __forceinline__ void epi_park(const f32x16 a1[2], const f32x16 a2[2],
                                         const float* __restrict__ bias,
                                         uint4* __restrict__ slot,
                                         int wu, int hi, int l) {
#pragma unroll
  for (int sf = 0; sf < 2; ++sf)
#pragma unroll
    for (int qq = 0; qq < 2; ++qq) {
      PK p[2];
#pragma unroll
      for (int h = 0; h < 2; ++h) {
        const int q = 2 * qq + h;
        const int ofb = 32 * wu + 8 * q + 4 * hi;
        const float4 bv = *(const float4*)(bias + ofb);
        const float v0 = fmaxf(fmaf(a2[sf][4*q+0], SPLIT_INV, a1[sf][4*q+0]) + bv.x, 0.f);
        const float v1 = fmaxf(fmaf(a2[sf][4*q+1], SPLIT_INV, a1[sf][4*q+1]) + bv.y, 0.f);
        const float v2 = fmaxf(fmaf(a2[sf][4*q+2], SPLIT_INV, a1[sf][4*q+2]) + bv.z, 0.f);
        const float v3 = fmaxf(fmaf(a2[sf][4*q+3], SPLIT_INV, a1[sf][4*q+3]) + bv.w, 0.f);
        p[h] = split4(v0, v1, v2, v3);
      }
      slot[(sf * 2 + qq) * 64 + l]     = make_uint4(p[0].hi.x, p[0].hi.y, p[1].hi.x, p[1].hi.y);
      slot[(4 + sf * 2 + qq) * 64 + l] = make_uint4(p[0].lo.x, p[0].lo.y, p[1].lo.x, p[1].lo.y);
    }
}

// unpark loaded uint4s -> X planes (mirror of epi_write positions).
__device__ __forceinline__ void unpark_write(const uint4 pk[8],
                                             _Float16* __restrict__ Xs,
                                             int wu, int col, int hi) {
#pragma unroll
  for (int sf = 0; sf < 2; ++sf) {
    _Float16* yrow = Xs + (32 * sf + col) * RSTR;
#pragma unroll
    for (int qq = 0; qq < 2; ++qq) {
      const uint4 h4 = pk[sf * 2 + qq];
      const uint4 l4 = pk[4 + sf * 2 + qq];
      const int ofb0 = 32 * wu + 8 * (2 * qq) + 4 * hi;
      const int ofb1 = ofb0 + 8;
      *(uint2*)(yrow + ofb0) = make_uint2(h4.x, h4.y);
      *(uint2*)(yrow + 288 + ofb0) = make_uint2(l4.x, l4.y);
      *(uint2*)(yrow + ofb1) = make_uint2(h4.z, h4.w);
      *(uint2*)(yrow + 288 + ofb1) = make_uint2(l4.z, l4.w);
    }
  }
}

__global__ __launch_bounds__(512, 4) void topdown_mfma(
    const float* __restrict__ towers, const float* __restrict__ aggregate,
    const float* __restrict__ O1b, const float* __restrict__ O2b,
    const float* __restrict__ O3w, const float* __restrict__ O3b,
    const float* __restrict__ M1b, const float* __restrict__ M2b,
    const float* __restrict__ M3b, float* __restrict__ out) {
  __shared__ __align__(16) _Float16 Xs[64 * RSTR];  // 74752 B
  __shared__ __align__(16) float scr[64][8];        // 2 KB cross-wave reduce
  const int t = threadIdx.x, l = t & 63;
  const int wu = __builtin_amdgcn_readfirstlane(t >> 6);  // wave id = of-eighth
  const int col = l & 31, hi = l >> 5;
  const int n0 = blockIdx.x * 64;
  uint4* park = g_park + ((size_t)blockIdx.x * 8 + (size_t)wu) * (8 * 64);

  // per-lane B-read bases: rows col (sf=0) and 32+col (sf=1), k-offset hi*8
  const _Float16* Xp0 = Xs + col * RSTR + hi * 8;
  const _Float16* Xp1 = Xs + (32 + col) * RSTR + hi * 8;

  // init X: logical features 0..255 = aggregate, 256..287 = 0 (both planes).
  for (int idx = t; idx < 64 * 288; idx += 512) {
    const int ss = idx / 288, f = idx - ss * 288;
    const float v = (f < 256) ? aggregate[f] : 0.f;
    _Float16 h, lo; split1(v, h, lo);
    Xs[ss * RSTR + f] = h;
    Xs[ss * RSTR + 288 + f] = lo;
  }

  float prod = 1.f;
  const float o3bias = O3b[0];
  f32x16 a1[2], a2[2];

  const uint4* WhL = (const uint4*)g_Wh + l;
  const uint4* WlL = (const uint4*)g_Wl + l;

  for (int kk = 0; kk < KS; ++kk) {
    const int tbase = (KS - 1 - kk) * 14;  // reference flips along K
    // tower slice -> logical features 256..269 (both planes)
    for (int idx = t; idx < 64 * 14; idx += 512) {
      const int ss = idx / 14, f = idx - ss * 14;
      const float v = towers[(size_t)(n0 + ss) * (KS * 14) + tbase + f];
      _Float16 h, lo; split1(v, h, lo);
      Xs[ss * RSTR + 256 + f] = h;
      Xs[ss * RSTR + 288 + 256 + f] = lo;
    }
    __syncthreads();  // (a) towers + previous A' visible

    // ---- M1 over X=[A,T]; result -> global park
    zero2(a1[0], a2[0]); zero2(a1[1], a2[1]);
    lgemm32<9>(a1[0], a1[1], a2[0], a2[1], Xp0, Xp1, WhL + 144 * 64, WlL + 144 * 64, wu);
    epi_park(a1, a2, M1b, park, wu, hi, l);

    // ---- O1 over X
    zero2(a1[0], a2[0]); zero2(a1[1], a2[1]);
    lgemm32<9>(a1[0], a1[1], a2[0], a2[1], Xp0, Xp1, WhL, WlL, wu);
    __syncthreads();  // (b) all X reads done; park stores in flight
    epi_write(a1, a2, O1b, Xs, wu, col, hi);  // X[0..255] <- h1
    __syncthreads();  // (c) h1 visible

    // ---- O2 over h1
    zero2(a1[0], a2[0]); zero2(a1[1], a2[1]);
    lgemm32<8>(a1[0], a1[1], a2[0], a2[1], Xp0, Xp1, WhL + 288 * 64, WlL + 288 * 64, wu);

    // unpark loads issued now (wave-private; latency hides under O3 tail)
    asm volatile("" ::: "memory");
    uint4 pk[8];
#pragma unroll
    for (int q = 0; q < 8; ++q) pk[q] = park[q * 64 + l];

    // O3 tail: relu(O2) dot O3w over this wave's 32 of -> per-sample partials
    float tp[2] = {0.f, 0.f};
#pragma unroll
    for (int sf = 0; sf < 2; ++sf)
#pragma unroll
      for (int q = 0; q < 4; ++q) {
        const int ofb = 32 * wu + 8 * q + 4 * hi;
        const float4 bv = *(const float4*)(O2b + ofb);
        const float4 ov = *(const float4*)(O3w + ofb);
        tp[sf] += fmaxf(fmaf(a2[sf][4*q+0], SPLIT_INV, a1[sf][4*q+0]) + bv.x, 0.f) * ov.x;
        tp[sf] += fmaxf(fmaf(a2[sf][4*q+1], SPLIT_INV, a1[sf][4*q+1]) + bv.y, 0.f) * ov.y;
        tp[sf] += fmaxf(fmaf(a2[sf][4*q+2], SPLIT_INV, a1[sf][4*q+2]) + bv.z, 0.f) * ov.z;
        tp[sf] += fmaxf(fmaf(a2[sf][4*q+3], SPLIT_INV, a1[sf][4*q+3]) + bv.w, 0.f) * ov.w;
      }
    tp[0] += __shfl_xor(tp[0], 32);  // combine hi-halves (k-split of the dot)
    tp[1] += __shfl_xor(tp[1], 32);
    if (hi == 0) {
      scr[col][wu] = tp[0];
      scr[32 + col][wu] = tp[1];
    }
    __syncthreads();  // (d) scr ready; all h1 reads done

    unpark_write(pk, Xs, wu, col, hi);  // X <- A' (M1 result)
    if (t < 64) {
      const float4 s0 = *(const float4*)(scr[t]);
      const float4 s1 = *(const float4*)(scr[t] + 4);
      const float tt = ((s0.x + s0.y) + (s0.z + s0.w)) +
                       ((s1.x + s1.y) + (s1.z + s1.w)) + o3bias;
      prod *= 1.f / (1.f + expf(-tt));
    }
    __syncthreads();  // (e) A' visible

    // ---- M2 (in place)
    zero2(a1[0], a2[0]); zero2(a1[1], a2[1]);
    lgemm32<8>(a1[0], a1[1], a2[0], a2[1], Xp0, Xp1, WhL + 416 * 64, WlL + 416 * 64, wu);
    __syncthreads();  // (f) reads done
    epi_write(a1, a2, M2b, Xs, wu, col, hi);
    __syncthreads();  // (g)

    // ---- M3 (in place); next-iter sync (a) covers the write->read edge
    zero2(a1[0], a2[0]); zero2(a1[1], a2[1]);
    lgemm32<8>(a1[0], a1[1], a2[0], a2[1], Xp0, Xp1, WhL + 544 * 64, WlL + 544 * 64, wu);
    __syncthreads();  // (h) reads done
    epi_write(a1, a2, M3b, Xs, wu, col, hi);
  }

  if (t < 64) out[n0 + t] = prod;
}

extern "C" void kernel_launch(void* const* d_in, const int* in_sizes, int n_in,
                              void* d_out, int out_size, void* d_ws, size_t ws_size,
                              hipStream_t stream) {
  const float* towers    = (const float*)d_in[0];
  const float* aggregate = (const float*)d_in[1];
  const float* M1w = (const float*)d_in[2];
  const float* M1b = (const float*)d_in[3];
  const float* M2w = (const float*)d_in[4];
  const float* M2b = (const float*)d_in[5];
  const float* M3w = (const float*)d_in[6];
  const float* M3b = (const float*)d_in[7];
  const float* O1w = (const float*)d_in[8];
  const float* O1b = (const float*)d_in[9];
  const float* O2w = (const float*)d_in[10];
  const float* O2b = (const float*)d_in[11];
  const float* O3w = (const float*)d_in[12];
  const float* O3b = (const float*)d_in[13];
  float* out = (float*)d_out;

  prep_w<<<672, 64, 0, stream>>>(O1w, M1w, O2w, M2w, M3w);

  const int nblocks = out_size / 64;  // 2048 blocks x 512 threads (8 waves)
  topdown_mfma<<<nblocks, 512, 0, stream>>>(towers, aggregate, O1b, O2b, O3w,
                                            O3b, M1b, M2b, M3b, out);
}

// Round 10
// 2340.409 us; speedup vs baseline: 1.3992x; 1.3042x over previous
//
#include <hip/hip_runtime.h>
#include <math.h>
#include <stdint.h>

// ============================================================================
// TopDownNet via split-f16 MFMA, R14: R9 skeleton + register-neutral VALU diet.
// R9 (2407us, best): of-eighth split, 16x16x32, 64-sample block, 8 waves,
// 16 waves/CU (exactly at the 128-reg/wave cap), MfmaUtil 57 + VALU 38 = 95%
// issue-busy. R10-R13 (all regressions) established: (1) raising per-wave
// weight-load:MFMA ratio loses; (2) 32x32 MFMA adds idle (fewer/longer
// dependency-chained ops); (3) LDS bank conflicts are NOT on the critical
// path (R13: conflicts -83%, still slower). R14 keeps R9 bit-identical in
// structure and shaves VALU issue:
//  - acc1 initialized to layer BIAS (epilogues drop 2 loads + 16 adds each);
//  - weight addressing via pointer bump (constant stride per chunk);
//  - register-neutral by design (bias consumed at init, not live in gemm).
// Split math (validated R5-R13, absmax 3.8e-6): x = xh + xl*2^-11, w likewise;
//   acc1 += xh*wh ; acc2 += xh*wl + xl*wh ; result = acc1 + acc2/2048.
// Fragment layouts (gfx950 16x16x32): A row=l&15 (of), k=(l>>4)*8+i;
//   B col=l&15 (sample), same k; D row=(l>>4)*4+r, col=l&15.
// ============================================================================

typedef _Float16 half8 __attribute__((ext_vector_type(8)));
typedef __fp16 fp16x2 __attribute__((ext_vector_type(2)));  // cvt_pkrtz native
typedef float f32x4 __attribute__((ext_vector_type(4)));

constexpr int KS = 10;
constexpr int RSTR = 584;  // f16/row: 288 hi + 288 lo + 8 pad
constexpr float SPLIT_S = 2048.f;
constexpr float SPLIT_INV = 1.f / 2048.f;

// W^T fragment streams (16x16 layout, verified R5-R10).
// Frag idx within layer: f = c*16 + nt. Layer bases: O1 0, M1 144, O2 288,
// M2 416, M3 544. Frag = 64 lanes x 8 f16 (1KB).
__device__ __align__(16) _Float16 g_Wh[672 * 512];
__device__ __align__(16) _Float16 g_Wl[672 * 512];
// M1 park: 2048 blocks x 8 waves x 8 uint4 x 64 lanes (wave-private slots).
__device__ __align__(16) uint4 g_park[2048u * 8u * 8u * 64u];

__global__ void prep_w(const float* __restrict__ O1w, const float* __restrict__ M1w,
                       const float* __restrict__ O2w, const float* __restrict__ M2w,
                       const float* __restrict__ M3w) {
  const int bid = blockIdx.x, l = threadIdx.x;
  const float* W; int Ksrc, f;
  if (bid < 144)      { W = O1w; Ksrc = 270; f = bid; }
  else if (bid < 288) { W = M1w; Ksrc = 270; f = bid - 144; }
  else if (bid < 416) { W = O2w; Ksrc = 256; f = bid - 288; }
  else if (bid < 544) { W = M2w; Ksrc = 256; f = bid - 416; }
  else                { W = M3w; Ksrc = 256; f = bid - 544; }
  const int c = f >> 4, nt = f & 15, g = l >> 4, s = l & 15;
  const int of = nt * 16 + s;
  union { half8 h; uint4 u; } hv, lv;
#pragma unroll
  for (int i = 0; i < 8; ++i) {
    const int k = c * 32 + g * 8 + i;
    const float w = (k < Ksrc) ? W[k * 256 + of] : 0.f;  // zero-pad K 270..287
    const _Float16 h = (_Float16)w;
    hv.h[i] = h;
    lv.h[i] = (_Float16)((w - (float)h) * SPLIT_S);
  }
  ((uint4*)g_Wh)[bid * 64 + l] = hv.u;
  ((uint4*)g_Wl)[bid * 64 + l] = lv.u;
}

__device__ __forceinline__ half8 as_half8(uint4 u) {
  union { uint4 u4; half8 h; } c; c.u4 = u; return c.h;
}
__device__ __forceinline__ f32x4 mfma16(half8 a, half8 b, f32x4 c) {
  return __builtin_amdgcn_mfma_f32_16x16x32_f16(a, b, c, 0, 0, 0);
}
__device__ __forceinline__ uint32_t h2bits(fp16x2 h) {
  union { fp16x2 h2; uint32_t u; } c; c.h2 = h; return c.u;
}

struct PK { uint2 hi, lo; };
// RTZ split-pack of 4 f32 -> 4 f16-hi + 4 f16-lo (residual * 2048).
__device__ __forceinline__ PK split4(float v0, float v1, float v2, float v3) {
  fp16x2 h01 = __builtin_amdgcn_cvt_pkrtz(v0, v1);
  fp16x2 h23 = __builtin_amdgcn_cvt_pkrtz(v2, v3);
  fp16x2 l01 = __builtin_amdgcn_cvt_pkrtz((v0 - (float)h01[0]) * SPLIT_S,
                                          (v1 - (float)h01[1]) * SPLIT_S);
  fp16x2 l23 = __builtin_amdgcn_cvt_pkrtz((v2 - (float)h23[0]) * SPLIT_S,
                                          (v3 - (float)h23[1]) * SPLIT_S);
  PK r;
  r.hi = make_uint2(h2bits(h01), h2bits(h23));
  r.lo = make_uint2(h2bits(l01), h2bits(l23));
  return r;
}
__device__ __forceinline__ void split1(float v, _Float16& h, _Float16& l) {
  h = (_Float16)v;
  l = (_Float16)((v - (float)h) * SPLIT_S);
}

// acc1 <- layer bias (per-lane slice), acc2 <- 0. Replaces zero-init + the
// epilogue bias add; bias values are consumed here (not live across the gemm).
__device__ __forceinline__ void binit24(f32x4 a1[2][4], f32x4 a2[2][4],
                                        const float* __restrict__ bias,
                                        int wu, int g) {
#pragma unroll
  for (int n = 0; n < 2; ++n) {
    const float4 bv = *(const float4*)(bias + (2 * wu + n) * 16 + 4 * g);
    const f32x4 b = {bv.x, bv.y, bv.z, bv.w};
#pragma unroll
    for (int sf = 0; sf < 4; ++sf) {
      a1[n][sf] = b;
      a2[n][sf] = (f32x4){0.f, 0.f, 0.f, 0.f};
    }
  }
}

// GEMM over CHUNKS K-chunks of 32: wave computes of-tiles {2wu, 2wu+1} for 64
// samples. Per c: 4 global dwordx4 (weights, pointer-bumped) + 8 ds_read_b128
// (B hi/lo) + 24 MFMA.
template <int CHUNKS>
__device__ __forceinline__ void lgemm(f32x4 a1[2][4], f32x4 a2[2][4],
                                      const _Float16* __restrict__ Xs,
                                      const uint4* __restrict__ Wh,
                                      const uint4* __restrict__ Wl,
                                      int wu, int g, int s) {
  const uint4* __restrict__ wph = Wh + 2 * wu * 64;
  const uint4* __restrict__ wpl = Wl + 2 * wu * 64;
#pragma unroll 1
  for (int c = 0; c < CHUNKS; ++c) {
    const uint4 h0 = wph[0], h1 = wph[64];
    const uint4 l0 = wpl[0], l1 = wpl[64];
    const half8 wh0 = as_half8(h0), wh1 = as_half8(h1);
    const half8 wl0 = as_half8(l0), wl1 = as_half8(l1);
#pragma unroll
    for (int sf = 0; sf < 4; ++sf) {
      const _Float16* xp = Xs + (16 * sf + s) * RSTR + c * 32 + g * 8;
      half8 bh = *(const half8*)xp;          // hi plane (16B aligned)
      half8 bl = *(const half8*)(xp + 288);  // lo plane
      a1[0][sf] = mfma16(wh0, bh, a1[0][sf]);
      a2[0][sf] = mfma16(wh0, bl, a2[0][sf]);
      a2[0][sf] = mfma16(wl0, bh, a2[0][sf]);
      a1[1][sf] = mfma16(wh1, bh, a1[1][sf]);
      a2[1][sf] = mfma16(wh1, bl, a2[1][sf]);
      a2[1][sf] = mfma16(wl1, bh, a2[1][sf]);
    }
    wph += 16 * 64;
    wpl += 16 * 64;
  }
}

// relu(acc1 + acc2/2048) split-packed into X planes (bias already in acc1).
__device__ __forceinline__ void epi_write(const f32x4 a1[2][4], const f32x4 a2[2][4],
                                          _Float16* __restrict__ Xs,
                                          int wu, int g, int s) {
#pragma unroll
  for (int n = 0; n < 2; ++n) {
#pragma unroll
    for (int sf = 0; sf < 4; ++sf) {
      const float v0 = fmaxf(fmaf(a2[n][sf][0], SPLIT_INV, a1[n][sf][0]), 0.f);
      const float v1 = fmaxf(fmaf(a2[n][sf][1], SPLIT_INV, a1[n][sf][1]), 0.f);
      const float v2 = fmaxf(fmaf(a2[n][sf][2], SPLIT_INV, a1[n][sf][2]), 0.f);
      const float v3 = fmaxf(fmaf(a2[n][sf][3], SPLIT_INV, a1[n][sf][3]), 0.f);
      const PK p = split4(v0, v1, v2, v3);
      _Float16* yp = Xs + (16 * sf + s) * RSTR + (2 * wu + n) * 16 + 4 * g;
      *(uint2*)yp = p.hi;
      *(uint2*)(yp + 288) = p.lo;
    }
  }
}

// M1 epilogue -> coalesced park in global (wave-private slot, 8 uint4/lane).
__device__ __forceinline__ void epi_park(const f32x4 a1[2][4], const f32x4 a2[2][4],
                                         uint4* __restrict__ slot, int l) {
#pragma unroll
  for (int n = 0; n < 2; ++n) {
#pragma unroll
    for (int p = 0; p < 2; ++p) {
      PK q[2];
#pragma unroll
      for (int h = 0; h < 2; ++h) {
        const int sf = 2 * p + h;
        const float v0 = fmaxf(fmaf(a2[n][sf][0], SPLIT_INV, a1[n][sf][0]), 0.f);
        const float v1 = fmaxf(fmaf(a2[n][sf][1], SPLIT_INV, a1[n][sf][1]), 0.f);
        const float v2 = fmaxf(fmaf(a2[n][sf][2], SPLIT_INV, a1[n][sf][2]), 0.f);
        const float v3 = fmaxf(fmaf(a2[n][sf][3], SPLIT_INV, a1[n][sf][3]), 0.f);
        q[h] = split4(v0, v1, v2, v3);
      }
      slot[(n * 2 + p) * 64 + l]     = make_uint4(q[0].hi.x, q[0].hi.y, q[1].hi.x, q[1].hi.y);
      slot[(4 + n * 2 + p) * 64 + l] = make_uint4(q[0].lo.x, q[0].lo.y, q[1].lo.x, q[1].lo.y);
    }
  }
}

// unpark loaded uint4s -> X planes.
__device__ __forceinline__ void unpark_write(const uint4 pk[8],
                                             _Float16* __restrict__ Xs,
                                             int wu, int g, int s) {
#pragma unroll
  for (int n = 0; n < 2; ++n)
#pragma unroll
    for (int p = 0; p < 2; ++p) {
      const uint4 hi = pk[n * 2 + p];
      const uint4 lo = pk[4 + n * 2 + p];
#pragma unroll
      for (int h = 0; h < 2; ++h) {
        const int sf = 2 * p + h;
        _Float16* yp = Xs + (16 * sf + s) * RSTR + (2 * wu + n) * 16 + 4 * g;
        *(uint2*)yp = h ? make_uint2(hi.z, hi.w) : make_uint2(hi.x, hi.y);
        *(uint2*)(yp + 288) = h ? make_uint2(lo.z, lo.w) : make_uint2(lo.x, lo.y);
      }
    }
}

__global__ __launch_bounds__(512, 4) void topdown_mfma(
    const float* __restrict__ towers, const float* __restrict__ aggregate,
    const float* __restrict__ O1b, const float* __restrict__ O2b,
    const float* __restrict__ O3w, const float* __restrict__ O3b,
    const float* __restrict__ M1b, const float* __restrict__ M2b,
    const float* __restrict__ M3b, float* __restrict__ out) {
  __shared__ __align__(16) _Float16 Xs[64 * RSTR];  // 74752 B
  __shared__ __align__(16) float scr[64][8];        // 2 KB cross-wave reduce
  const int t = threadIdx.x, l = t & 63;
  const int wu = __builtin_amdgcn_readfirstlane(t >> 6);  // wave id = of-eighth
  const int g = l >> 4, s = l & 15;
  const int n0 = blockIdx.x * 64;
  uint4* park = g_park + ((size_t)blockIdx.x * 8 + (size_t)wu) * (8 * 64);

  // init X: logical features 0..255 = aggregate, 256..287 = 0 (both planes).
  for (int idx = t; idx < 64 * 288; idx += 512) {
    const int ss = idx / 288, f = idx - ss * 288;
    const float v = (f < 256) ? aggregate[f] : 0.f;
    _Float16 h, lo; split1(v, h, lo);
    Xs[ss * RSTR + f] = h;
    Xs[ss * RSTR + 288 + f] = lo;
  }

  float prod = 1.f;
  const float o3bias = O3b[0];
  f32x4 a1[2][4], a2[2][4];

  const uint4* WhL = (const uint4*)g_Wh + l;
  const uint4* WlL = (const uint4*)g_Wl + l;

  for (int kk = 0; kk < KS; ++kk) {
    const int tbase = (KS - 1 - kk) * 14;  // reference flips along K
    // tower slice -> logical features 256..269 (both planes)
    for (int idx = t; idx < 64 * 14; idx += 512) {
      const int ss = idx / 14, f = idx - ss * 14;
      const float v = towers[(size_t)(n0 + ss) * (KS * 14) + tbase + f];
      _Float16 h, lo; split1(v, h, lo);
      Xs[ss * RSTR + 256 + f] = h;
      Xs[ss * RSTR + 288 + 256 + f] = lo;
    }
    __syncthreads();  // (a) towers + previous A' visible

    // ---- M1 over X=[A,T]; result -> global park
    binit24(a1, a2, M1b, wu, g);
    lgemm<9>(a1, a2, Xs, WhL + 144 * 64, WlL + 144 * 64, wu, g, s);
    epi_park(a1, a2, park, l);

    // ---- O1 over X
    binit24(a1, a2, O1b, wu, g);
    lgemm<9>(a1, a2, Xs, WhL, WlL, wu, g, s);
    __syncthreads();  // (b) all X reads done; park stores drained
    epi_write(a1, a2, Xs, wu, g, s);  // X[0..255] <- h1
    __syncthreads();  // (c) h1 visible

    // ---- O2 over h1 (acc1 pre-loaded with O2 bias)
    binit24(a1, a2, O2b, wu, g);
    lgemm<8>(a1, a2, Xs, WhL + 288 * 64, WlL + 288 * 64, wu, g, s);

    // unpark loads issued now (wave-private; latency hides under O3 tail)
    asm volatile("" ::: "memory");
    uint4 pk[8];
#pragma unroll
    for (int q = 0; q < 8; ++q) pk[q] = park[q * 64 + l];

    // O3 tail: relu(O2) dot O3w -> per-sample partials (bias already in acc)
    float tp[2] = {0.f, 0.f};
#pragma unroll
    for (int n = 0; n < 2; ++n) {
      const int ob = (2 * wu + n) * 16 + 4 * g;
      const float4 ov = *(const float4*)(O3w + ob);
      const float oo[4] = {ov.x, ov.y, ov.z, ov.w};
#pragma unroll
      for (int sf = 0; sf < 2; ++sf)
#pragma unroll
        for (int r = 0; r < 4; ++r)
          tp[sf] += fmaxf(fmaf(a2[n][sf][r], SPLIT_INV, a1[n][sf][r]), 0.f) * oo[r];
    }
    // sf=2,3 partials accumulate into tp via the same pattern
#pragma unroll
    for (int n = 0; n < 2; ++n) {
      const int ob = (2 * wu + n) * 16 + 4 * g;
      const float4 ov = *(const float4*)(O3w + ob);
      const float oo[4] = {ov.x, ov.y, ov.z, ov.w};
#pragma unroll
      for (int sf = 2; sf < 4; ++sf)
#pragma unroll
        for (int r = 0; r < 4; ++r)
          tp[sf - 2] += 0.f * oo[r];  // placeholder keeps structure; real below
    }
    // NOTE: R9 used tp[4]; restored exactly below (the above tp[2] covers
    // sf 0..1 only) -- recompute properly for all 4 sample-frags:
    float tq[4] = {tp[0], tp[1], 0.f, 0.f};
#pragma unroll
    for (int n = 0; n < 2; ++n) {
      const int ob = (2 * wu + n) * 16 + 4 * g;
      const float4 ov = *(const float4*)(O3w + ob);
      const float oo[4] = {ov.x, ov.y, ov.z, ov.w};
#pragma unroll
      for (int sf = 2; sf < 4; ++sf)
#pragma unroll
        for (int r = 0; r < 4; ++r)
          tq[sf] += fmaxf(fmaf(a2[n][sf][r], SPLIT_INV, a1[n][sf][r]), 0.f) * oo[r];
    }
#pragma unroll
    for (int sf = 0; sf < 4; ++sf) {  // sum over the 4 g-groups
      tq[sf] += __shfl_xor(tq[sf], 16);
      tq[sf] += __shfl_xor(tq[sf], 32);
    }
    if (g == 0) {
#pragma unroll
      for (int sf = 0; sf < 4; ++sf) scr[16 * sf + s][wu] = tq[sf];
    }
    __syncthreads();  // (d) scr ready; all h1 reads done

    unpark_write(pk, Xs, wu, g, s);  // X <- A' (M1 result)
    if (t < 64) {
      const float4 s0 = *(const float4*)(scr[t]);
      const float4 s1 = *(const float4*)(scr[t] + 4);
      const float tt = ((s0.x + s0.y) + (s0.z + s0.w)) +
                       ((s1.x + s1.y) + (s1.z + s1.w)) + o3bias;
      prod *= 1.f / (1.f + expf(-tt));
    }
    __syncthreads();  // (e) A' visible

    // ---- M2 (in place)
    binit24(a1, a2, M2b, wu, g);
    lgemm<8>(a1, a2, Xs, WhL + 416 * 64, WlL + 416 * 64, wu, g, s);
    __syncthreads();  // (f) reads done
    epi_write(a1, a2, Xs, wu, g, s);
    __syncthreads();  // (g)

    // ---- M3 (in place); next-iter sync (a) covers the write->read edge
    binit24(a1, a2, M3b, wu, g);
    lgemm<8>(a1, a2, Xs, WhL + 544 * 64, WlL + 544 * 64, wu, g, s);
    __syncthreads();  // (h) reads done
    epi_write(a1, a2, Xs, wu, g, s);
  }

  if (t < 64) out[n0 + t] = prod;
}

extern "C" void kernel_launch(void* const* d_in, const int* in_sizes, int n_in,
                              void* d_out, int out_size, void* d_ws, size_t ws_size,
                              hipStream_t stream) {
  const float* towers    = (const float*)d_in[0];
  const float* aggregate = (const float*)d_in[1];
  const float* M1w = (const float*)d_in[2];
  const float* M1b = (const float*)d_in[3];
  const float* M2w = (const float*)d_in[4];
  const float* M2b = (const float*)d_in[5];
  const float* M3w = (const float*)d_in[6];
  const float* M3b = (const float*)d_in[7];
  const float* O1w = (const float*)d_in[8];
  const float* O1b = (const float*)d_in[9];
  const float* O2w = (const float*)d_in[10];
  const float* O2b = (const float*)d_in[11];
  const float* O3w = (const float*)d_in[12];
  const float* O3b = (const float*)d_in[13];
  float* out = (float*)d_out;

  prep_w<<<672, 64, 0, stream>>>(O1w, M1w, O2w, M2w, M3w);

  const int nblocks = out_size / 64;  // 2048 blocks x 512 threads (8 waves)
  topdown_mfma<<<nblocks, 512, 0, stream>>>(towers, aggregate, O1b, O2b, O3w,
                                            O3b, M1b, M2b, M3b, out);
}